// Round 1
// 1334.344 us; speedup vs baseline: 1.0833x; 1.0833x over previous
//
#include <hip/hip_runtime.h>
#include <hip/hip_bf16.h>

#define T_TOK 4096
#define H_DIM 2048
#define I_DIM 1408
#define KEXP 8
#define E_TOT 16
#define KDIM2 (KEXP * I_DIM)   // 11264

typedef __attribute__((ext_vector_type(8))) short short8;
typedef __attribute__((ext_vector_type(4))) float floatx4;

__device__ __forceinline__ unsigned short f2bf(float f) {
  unsigned int u = __builtin_bit_cast(unsigned int, f);
  u += 0x7fffu + ((u >> 16) & 1u);   // RNE
  return (unsigned short)(u >> 16);
}

#define GLD16(gp, lp) \
  __builtin_amdgcn_global_load_lds((const __attribute__((address_space(1))) unsigned int*)(gp), \
                                   (__attribute__((address_space(3))) unsigned int*)(lp), 16, 0, 0)

// ---------------- fp32 -> bf16 flat convert (X) ----------------
__global__ __launch_bounds__(256) void k_convert_x(const float* __restrict__ in,
                                                   unsigned short* __restrict__ out, int n4) {
  int i = blockIdx.x * 256 + threadIdx.x;
  if (i >= n4) return;
  floatx4 v = ((const floatx4*)in)[i];
  union { unsigned short s[4]; unsigned long long u; } o;
  o.s[0] = f2bf(v.x); o.s[1] = f2bf(v.y); o.s[2] = f2bf(v.z); o.s[3] = f2bf(v.w);
  ((unsigned long long*)out)[i] = o.u;
}

// ---------------- fp32 -> bf16 tiled transpose, vectorized stores ----------------
__global__ __launch_bounds__(256) void k_transpose_bf(const float* __restrict__ in,
    unsigned short* __restrict__ out, int C, long inBatch, long outStride, long outBatch) {
  __shared__ unsigned short ldsT[32][68];
  const int tid = threadIdx.x;
  const int c = tid & 31;
  const int r8 = tid >> 5;                 // 0..7
  const long zin = (long)blockIdx.z * inBatch;
  const int x0 = blockIdx.x * 32;          // c offset
  const int y0 = blockIdx.y * 64;          // r offset
  const float* ip = in + zin + (long)(y0 + r8) * C + x0 + c;
#pragma unroll
  for (int j = 0; j < 8; j++)
    ldsT[c][r8 + 8 * j] = f2bf(ip[(long)(8 * j) * C]);
  __syncthreads();
  const long zout = (long)blockIdx.z * outBatch;
#pragma unroll
  for (int p = 0; p < 2; p++) {
    int u = tid + 256 * p;
    int cc = u >> 4;                       // 0..31
    int rg = u & 15;                       // 0..15 (4 r's each)
    unsigned long long v = *(const unsigned long long*)&ldsT[cc][rg * 4];
    *(unsigned long long*)(out + (long)(x0 + cc) * outStride + zout + y0 + rg * 4) = v;
  }
}

// ---------------- router: logits -> top8 softmax weights ----------------
__global__ __launch_bounds__(64) void k_router(const float* __restrict__ X,
    const float* __restrict__ Wr, float* __restrict__ rw_out, float* __restrict__ rw_ws) {
  const int t = blockIdx.x;
  const int lane = threadIdx.x;
  float acc[E_TOT];
#pragma unroll
  for (int e = 0; e < E_TOT; e++) acc[e] = 0.f;
  const float* xr = X + (size_t)t * H_DIM;
  for (int h = lane; h < H_DIM; h += 64) {
    float xv = xr[h];
    const float* w = Wr + (size_t)h * E_TOT;
#pragma unroll
    for (int e = 0; e < E_TOT; e++) acc[e] += xv * w[e];
  }
#pragma unroll
  for (int off = 32; off > 0; off >>= 1) {
#pragma unroll
    for (int e = 0; e < E_TOT; e++) acc[e] += __shfl_down(acc[e], off);
  }
  if (lane == 0) {
    float v[E_TOT];
#pragma unroll
    for (int e = 0; e < E_TOT; e++) v[e] = acc[e];
    float top[KEXP];
    for (int j = 0; j < KEXP; j++) {        // selection of top-8, descending
      int bi = 0; float bv = v[0];
      for (int e = 1; e < E_TOT; e++) { if (v[e] > bv) { bv = v[e]; bi = e; } }
      top[j] = bv; v[bi] = -1e30f;
    }
    float m = top[0], s = 0.f, ex[KEXP];
    for (int j = 0; j < KEXP; j++) { ex[j] = __expf(top[j] - m); s += ex[j]; }
    float inv = 1.f / s;
    for (int j = 0; j < KEXP; j++) {
      float w = ex[j] * inv;
      rw_out[t * KEXP + j] = w;
      rw_ws[t * KEXP + j] = w;
    }
  }
}

// ---------------- GEMM1: prefetch-pipelined, swizzled, XCD-chunked ----------------
// hid'[t][ke*I+i] = rw[t,ke] * silu(gate) * up
__global__ __launch_bounds__(256, 2) void k_gemm1(
    const unsigned short* __restrict__ Xb, const unsigned short* __restrict__ GUT,
    const float* __restrict__ rw, unsigned short* __restrict__ hid) {
  __shared__ unsigned short lA[2][128 * 32];
  __shared__ unsigned short lG[2][64 * 32];
  __shared__ unsigned short lU[2][64 * 32];
  __shared__ float rwS[128];

  const int tid = threadIdx.x;
  const int lane = tid & 63;
  const int wid = tid >> 6;

  // XCD-chunked bijective remap: 5632 = 8 * 704 -> one expert per XCD,
  // n-tile (x) fastest so the 512KB A-panel stays L2-resident across its 22 n-blocks.
  const int wg = (blockIdx.x & 7) * 704 + (blockIdx.x >> 3);
  const int bx = wg % 22;
  const int t1 = wg / 22;
  const int n0 = bx * 64;
  const int m0 = (t1 & 31) * 128;
  const int ke = t1 >> 5;

  if (tid < 128) rwS[tid] = rw[(m0 + tid) * KEXP + ke];

  const unsigned short* Gq = GUT + (size_t)ke * (2 * I_DIM * H_DIM) + (size_t)n0 * H_DIM;
  const unsigned short* Uq = Gq + (size_t)I_DIM * H_DIM;

  // staging: thread tid writes LDS row srow (and srow+64), 16B slot (tid&3), linearly.
  // Pre-swizzle the GLOBAL source slot by ((row>>1)&3) so that the swizzled ds_read
  // below recovers the identity (XOR is its own inverse). LDS dest stays linear
  // as global_load_lds requires.
  const int srow = tid >> 2;
  const int scol8 = ((tid & 3) ^ ((tid >> 3) & 3)) * 8;
  const unsigned short* pA  = Xb + (size_t)(m0 + srow) * H_DIM + scol8;
  const unsigned short* pA2 = pA + (size_t)64 * H_DIM;
  const unsigned short* pG  = Gq + (size_t)srow * H_DIM + scol8;
  const unsigned short* pU  = Uq + (size_t)srow * H_DIM + scol8;

  floatx4 accg[4][2], accu[4][2];
  const floatx4 zero = {0.f, 0.f, 0.f, 0.f};
#pragma unroll
  for (int i = 0; i < 4; i++)
#pragma unroll
    for (int j = 0; j < 2; j++) { accg[i][j] = zero; accu[i][j] = zero; }

  const int wm = (wid >> 1) * 64;
  const int wn = (wid & 1) * 32;
  const int lr = lane & 15;
  const int lq = lane >> 4;
  // fragment-row bases are =0 mod 16, so the swizzle key reduces to (lr>>1)&3:
  const int lsw8 = (lq ^ ((lr >> 1) & 3)) * 8;

#define STAGE1(B, H0) do { \
    GLD16(pA  + (H0), &lA[B][tid * 8]); \
    GLD16(pA2 + (H0), &lA[B][2048 + tid * 8]); \
    GLD16(pG  + (H0), &lG[B][tid * 8]); \
    GLD16(pU  + (H0), &lU[B][tid * 8]); \
  } while (0)

#define COMP1(B) do { \
    short8 af[4], gf[2], uf[2]; \
    _Pragma("unroll") \
    for (int mt = 0; mt < 4; mt++) \
      af[mt] = *(const short8*)(&lA[B][(wm + mt * 16 + lr) * 32 + lsw8]); \
    _Pragma("unroll") \
    for (int nt = 0; nt < 2; nt++) { \
      gf[nt] = *(const short8*)(&lG[B][(wn + nt * 16 + lr) * 32 + lsw8]); \
      uf[nt] = *(const short8*)(&lU[B][(wn + nt * 16 + lr) * 32 + lsw8]); \
    } \
    _Pragma("unroll") \
    for (int mt = 0; mt < 4; mt++) \
      _Pragma("unroll") \
      for (int nt = 0; nt < 2; nt++) { \
        accg[mt][nt] = __builtin_amdgcn_mfma_f32_16x16x32_bf16(af[mt], gf[nt], accg[mt][nt], 0, 0, 0); \
        accu[mt][nt] = __builtin_amdgcn_mfma_f32_16x16x32_bf16(af[mt], uf[nt], accu[mt][nt], 0, 0, 0); \
      } \
  } while (0)

  STAGE1(0, 0);
  __syncthreads();
  for (int h0 = 0; h0 < H_DIM; h0 += 64) {
    STAGE1(1, h0 + 32);          // prefetch next tile while computing current
    COMP1(0);
    __syncthreads();
    if (h0 + 64 < H_DIM) STAGE1(0, h0 + 64);
    COMP1(1);
    __syncthreads();
  }
#undef STAGE1
#undef COMP1

#pragma unroll
  for (int mt = 0; mt < 4; mt++) {
#pragma unroll
    for (int nt = 0; nt < 2; nt++) {
#pragma unroll
      for (int r = 0; r < 4; r++) {
        int lrow = wm + mt * 16 + lq * 4 + r;
        int col = n0 + wn + nt * 16 + lr;
        float g = accg[mt][nt][r];
        float u = accu[mt][nt][r];
        float s = g / (1.f + __expf(-g));
        float hv = s * u * rwS[lrow];
        hid[(size_t)(m0 + lrow) * KDIM2 + ke * I_DIM + col] = f2bf(hv);
      }
    }
  }
}

// ---------------- GEMM2: no split-K, prefetch-pipelined, swizzled, XCD-chunked ----
__global__ __launch_bounds__(256, 2) void k_gemm2(
    const unsigned short* __restrict__ Ah, const unsigned short* __restrict__ Bt,
    float* __restrict__ out) {
  __shared__ unsigned short lA[2][128 * 32];
  __shared__ unsigned short lB[2][128 * 32];
  const int tid = threadIdx.x;
  const int lane = tid & 63;
  const int wid = tid >> 6;

  // 512 = 8 * 64; x (n-tile) fastest -> 2.75MB A-panel L2-resident per n-sweep.
  const int wg = (blockIdx.x & 7) * 64 + (blockIdx.x >> 3);
  const int n0 = (wg & 15) * 128;
  const int m0 = (wg >> 4) * 128;

  const int srow = tid >> 2;
  const int scol8 = ((tid & 3) ^ ((tid >> 3) & 3)) * 8;
  const unsigned short* pA  = Ah + (size_t)(m0 + srow) * KDIM2 + scol8;
  const unsigned short* pA2 = pA + (size_t)64 * KDIM2;
  const unsigned short* pB  = Bt + (size_t)(n0 + srow) * KDIM2 + scol8;
  const unsigned short* pB2 = pB + (size_t)64 * KDIM2;

  floatx4 acc[4][4];
  const floatx4 zero = {0.f, 0.f, 0.f, 0.f};
#pragma unroll
  for (int i = 0; i < 4; i++)
#pragma unroll
    for (int j = 0; j < 4; j++) acc[i][j] = zero;

  const int wm = (wid >> 1) * 64;
  const int wn = (wid & 1) * 64;
  const int lr = lane & 15;
  const int lq = lane >> 4;
  const int lsw8 = (lq ^ ((lr >> 1) & 3)) * 8;

#define STAGE2(B, K0) do { \
    GLD16(pA  + (K0), &lA[B][tid * 8]); \
    GLD16(pA2 + (K0), &lA[B][2048 + tid * 8]); \
    GLD16(pB  + (K0), &lB[B][tid * 8]); \
    GLD16(pB2 + (K0), &lB[B][2048 + tid * 8]); \
  } while (0)

#define COMP2(B) do { \
    short8 af[4], bfr[4]; \
    _Pragma("unroll") \
    for (int mt = 0; mt < 4; mt++) \
      af[mt] = *(const short8*)(&lA[B][(wm + mt * 16 + lr) * 32 + lsw8]); \
    _Pragma("unroll") \
    for (int nt = 0; nt < 4; nt++) \
      bfr[nt] = *(const short8*)(&lB[B][(wn + nt * 16 + lr) * 32 + lsw8]); \
    _Pragma("unroll") \
    for (int mt = 0; mt < 4; mt++) \
      _Pragma("unroll") \
      for (int nt = 0; nt < 4; nt++) \
        acc[mt][nt] = __builtin_amdgcn_mfma_f32_16x16x32_bf16(af[mt], bfr[nt], acc[mt][nt], 0, 0, 0); \
  } while (0)

  STAGE2(0, 0);
  __syncthreads();
  for (int k0 = 0; k0 < KDIM2; k0 += 64) {
    STAGE2(1, k0 + 32);
    COMP2(0);
    __syncthreads();
    if (k0 + 64 < KDIM2) STAGE2(0, k0 + 64);
    COMP2(1);
    __syncthreads();
  }
#undef STAGE2
#undef COMP2

#pragma unroll
  for (int mt = 0; mt < 4; mt++)
#pragma unroll
    for (int nt = 0; nt < 4; nt++)
#pragma unroll
      for (int r = 0; r < 4; r++)
        out[(size_t)(m0 + wm + mt * 16 + lq * 4 + r) * H_DIM + (n0 + wn + nt * 16 + lr)] =
            acc[mt][nt][r];
}

__global__ void k_ws_fail(float* out) {
  if (threadIdx.x == 0 && blockIdx.x == 0) out[0] = 1.0e6f;
}

extern "C" void kernel_launch(void* const* d_in, const int* in_sizes, int n_in,
                              void* d_out, int out_size, void* d_ws, size_t ws_size,
                              hipStream_t stream) {
  const float* X  = (const float*)d_in[0];
  const float* Wr = (const float*)d_in[1];
  const float* GU = (const float*)d_in[2];
  const float* DW = (const float*)d_in[3];
  float* out = (float*)d_out;
  float* rw_out = out + (size_t)T_TOK * H_DIM;

  const size_t oX   = 0;
  const size_t oGUT = oX   + (size_t)T_TOK * H_DIM * 2;                 // 16.8 MB
  const size_t oDT  = oGUT + (size_t)KEXP * 2 * I_DIM * H_DIM * 2;      // +92.3 MB
  const size_t oHid = oDT  + (size_t)KEXP * I_DIM * H_DIM * 2;          // +46.1 MB
  const size_t oRW  = oHid + (size_t)T_TOK * KDIM2 * 2;                 // +92.3 MB
  const size_t need = oRW  + (size_t)T_TOK * KEXP * 4;                  // ~236 MiB

  if (ws_size < need) {
    k_ws_fail<<<1, 64, 0, stream>>>(out);
    return;
  }

  unsigned short* Xb  = (unsigned short*)((char*)d_ws + oX);
  unsigned short* GUT = (unsigned short*)((char*)d_ws + oGUT);
  unsigned short* DT  = (unsigned short*)((char*)d_ws + oDT);
  unsigned short* Hid = (unsigned short*)((char*)d_ws + oHid);
  float* rwW = (float*)((char*)d_ws + oRW);

  // 1) convert X to bf16
  k_convert_x<<<dim3((T_TOK * H_DIM / 4 + 255) / 256), 256, 0, stream>>>(X, Xb, T_TOK * H_DIM / 4);

  // 2) transpose+convert gate_up[:8]: [e][h][d] -> GUT [e][d][h]
  k_transpose_bf<<<dim3(2 * I_DIM / 32, H_DIM / 64, KEXP), 256, 0, stream>>>(
      GU, GUT, 2 * I_DIM, (long)H_DIM * 2 * I_DIM, (long)H_DIM, (long)2 * I_DIM * H_DIM);

  // 3) transpose+convert down[:8]: [k][i][h] -> DT [h][k*I+i]
  k_transpose_bf<<<dim3(H_DIM / 32, I_DIM / 64, KEXP), 256, 0, stream>>>(
      DW, DT, H_DIM, (long)I_DIM * H_DIM, (long)KDIM2, (long)I_DIM);

  // 4) router
  k_router<<<dim3(T_TOK), 64, 0, stream>>>(X, Wr, rw_out, rwW);

  // 5) GEMM1 + silu*up*rw -> hid'   (1D grid, XCD-chunked internally)
  k_gemm1<<<dim3((I_DIM / 64) * (T_TOK / 128) * KEXP), 256, 0, stream>>>(Xb, GUT, rwW, Hid);

  // 6) GEMM2 (full K, direct fp32 output)
  k_gemm2<<<dim3((H_DIM / 128) * (T_TOK / 128)), 256, 0, stream>>>(Hid, DT, out);
}